// Round 5
// baseline (1022.489 us; speedup 1.0000x reference)
//
#include <hip/hip_runtime.h>

#define NN 50000
#define NE 640000
#define NR 3
#define DH 128

#define BK 256                 // nodes per bucket
#define NBK 196                // buckets per relation: ceil(50000/256)
#define NBT (NR * NBK)         // 588 total buckets
#define CAP 4096               // bucket capacity (mean 3265, sigma 57)

typedef __attribute__((ext_vector_type(8))) short short8;
typedef __attribute__((ext_vector_type(4))) float f32x4;

__device__ __forceinline__ float bf2f(uint u) { return __uint_as_float(u << 16); }
__device__ __forceinline__ uint f2bf(float f) {
    uint u = __float_as_uint(f);
    u += 0x7fff + ((u >> 16) & 1);  // round-to-nearest-even
    return u >> 16;
}
__device__ __forceinline__ uint pack2(float a, float b) { return f2bf(a) | (f2bf(b) << 16); }

// ---------------- level 1: bucket edges by dst>>8, pack (src<<8)|dstLow ----------------
__global__ __launch_bounds__(256) void bucket_kernel(const int* __restrict__ ei,
                                                     int* __restrict__ bcnt,
                                                     uint* __restrict__ pairs) {
    int gid = blockIdx.x * 256 + threadIdx.x;
    if (gid >= NR * NE) return;
    int r = gid / NE, e = gid - r * NE;
    int src = ei[r * 2 * NE + e];
    int dst = ei[r * 2 * NE + NE + e];
    int b = r * NBK + (dst >> 8);
    int pos = atomicAdd(&bcnt[b], 1);
    if (pos < CAP) pairs[(size_t)b * CAP + pos] = ((uint)src << 8) | (uint)(dst & 255);
}

// ---------------- bucket-base exclusive scan (588 values, 1 block) ----------------
__global__ __launch_bounds__(1024) void bscan_kernel(const int* __restrict__ bcnt,
                                                     int* __restrict__ bbase) {
    int t = threadIdx.x;
    int v = (t < NBT) ? min(bcnt[t], CAP) : 0;
    int lane = t & 63, w = t >> 6;
    int s = v;
#pragma unroll
    for (int d = 1; d < 64; d <<= 1) {
        int u = __shfl_up(s, d);
        if (lane >= d) s += u;
    }
    __shared__ int ws[16];
    if (lane == 63) ws[w] = s;
    __syncthreads();
    if (t < 16) {
        int wv = ws[t];
#pragma unroll
        for (int d = 1; d < 16; d <<= 1) {
            int u = __shfl_up(wv, d);
            if (t >= d) wv += u;
        }
        ws[t] = wv;
    }
    __syncthreads();
    int incl = s + (w == 0 ? 0 : ws[w - 1]);
    if (t < NBT) bbase[t] = incl - v;  // exclusive
}

// ---------------- level 2: per-bucket LDS histogram + scan + scatter ----------------
__global__ __launch_bounds__(256) void csr_kernel(const uint* __restrict__ pairs,
                                                  const int* __restrict__ bcnt,
                                                  const int* __restrict__ bbase,
                                                  int* __restrict__ csr,
                                                  int* __restrict__ offs,
                                                  int* __restrict__ deg) {
    int b = blockIdx.x;            // 0..587
    int r = b / NBK;
    int n0 = (b - r * NBK) * BK;   // first node (within relation)
    int cnt = min(bcnt[b], CAP);
    int base = bbase[b];
    int t = threadIdx.x;

    __shared__ int hist[BK];
    __shared__ int cur[BK];
    __shared__ int ws[4];
    hist[t] = 0;
    __syncthreads();
    const uint* pp = pairs + (size_t)b * CAP;
    for (int i = t; i < cnt; i += 256) atomicAdd(&hist[pp[i] & 255u], 1);
    __syncthreads();

    // exclusive scan of hist[256]
    int lane = t & 63, w = t >> 6;
    int v = hist[t], s = v;
#pragma unroll
    for (int d = 1; d < 64; d <<= 1) {
        int u = __shfl_up(s, d);
        if (lane >= d) s += u;
    }
    if (lane == 63) ws[w] = s;
    __syncthreads();
    int add = 0;
#pragma unroll
    for (int q = 0; q < 3; ++q)
        if (q < w) add += ws[q];
    int excl = s + add - v;

    int node = n0 + t;
    if (node < NN) {
        offs[r * NN + node] = base + excl;  // absolute into csr
        deg[r * NN + node] = v;
    }
    cur[t] = excl;
    __syncthreads();

    for (int i = t; i < cnt; i += 256) {
        uint pk = pp[i];
        int pos = atomicAdd(&cur[pk & 255u], 1);
        csr[base + pos] = (int)(pk >> 8);
    }
}

// ---------------- weight prep: pack W into MFMA B-fragment layout, hi/lo bf16 split
__global__ __launch_bounds__(256) void prep_kernel(const float* __restrict__ Wn,
                                                   const float* __restrict__ Wr,
                                                   const float* __restrict__ linW,
                                                   ushort* __restrict__ Wpack) {
    int tid = blockIdx.x * 256 + threadIdx.x;
    if (tid >= 264 * 64) return;
    int f = tid >> 6, lane = tid & 63;
    int l15 = lane & 15, l4 = lane >> 4;
    ushort hi8[8], lo8[8];
    if (f < 256) {
        int layer = f >> 7, seg = (f >> 5) & 3, kc = (f >> 3) & 3, nb = f & 7;
        int col = nb * 16 + l15;
        int kb = kc * 32 + l4 * 8;
#pragma unroll
        for (int e = 0; e < 8; ++e) {
            int k = kb + e;
            float v;
            if (seg < 3) {
                v = Wn[(((size_t)layer * 3 + seg) * 128 + k) * 128 + col];
            } else {
                const float* base = Wr + (size_t)layer * 3 * 16384;
                v = base[k * 128 + col] + base[16384 + k * 128 + col] +
                    base[32768 + k * 128 + col];
            }
            uint h = f2bf(v);
            float rem = v - bf2f(h);
            hi8[e] = (ushort)h;
            lo8[e] = (ushort)f2bf(rem);
        }
    } else {
        int g = f - 256;
        int kc = g >> 1, nb = g & 1;
        int col = nb * 16 + l15;
        int kb = kc * 32 + l4 * 8;
#pragma unroll
        for (int e = 0; e < 8; ++e) {
            float v = linW[(kb + e) * 32 + col];
            uint h = f2bf(v);
            float rem = v - bf2f(h);
            hi8[e] = (ushort)h;
            lo8[e] = (ushort)f2bf(rem);
        }
    }
    *(short8*)(Wpack + (size_t)f * 1024 + lane * 8) = *(short8*)hi8;
    *(short8*)(Wpack + (size_t)f * 1024 + 512 + lane * 8) = *(short8*)lo8;
}

__global__ __launch_bounds__(256) void bias_kernel(const float* __restrict__ bc,
                                                   float* __restrict__ bsum) {
    int tid = threadIdx.x;
    int l = tid >> 7, j = tid & 127;
    const float* bb = bc + l * 3 * DH;
    bsum[tid] = bb[j] + bb[DH + j] + bb[2 * DH + j];
}

__global__ __launch_bounds__(256) void conv_kernel(const float* __restrict__ x,
                                                   ushort* __restrict__ xb) {
    int gid = blockIdx.x * 256 + threadIdx.x;
    if (gid >= NN * DH / 4) return;
    float4 v = ((const float4*)x)[gid];
    uint2 o;
    o.x = pack2(v.x, v.y);
    o.y = pack2(v.z, v.w);
    ((uint2*)xb)[gid] = o;
}

// ---------------- aggregation: one wave per (rel,node); 4 edge-rows per vmem instr
// lane = eg*16 + cs: edge-slot eg (0..3), col-segment cs (0..15, 8 bf16 = 16B each)
__global__ __launch_bounds__(256) void aggr_kernel(const ushort* __restrict__ tb,
                                                   ushort* __restrict__ mean_b,
                                                   const int* __restrict__ csr,
                                                   const int* __restrict__ offs,
                                                   const int* __restrict__ deg) {
    int wid = (blockIdx.x * 256 + threadIdx.x) >> 6;
    wid = __builtin_amdgcn_readfirstlane(wid);
    if (wid >= NR * NN) return;
    int lane = threadIdx.x & 63;
    int eg = lane >> 4, cs = lane & 15;
    int base = offs[wid];
    int d = deg[wid];
    const int* lst = csr + base;

    float a[8] = {0.f, 0.f, 0.f, 0.f, 0.f, 0.f, 0.f, 0.f};
    for (int e = 0; e < d; e += 16) {  // 16 edges per iteration, 4 dwordx4 in flight
        uint4 v[4];
        int ee[4];
#pragma unroll
        for (int q = 0; q < 4; ++q) {
            ee[q] = e + q * 4 + eg;
            int idx = lst[min(ee[q], d - 1)];
            v[q] = *(const uint4*)(tb + (size_t)idx * DH + cs * 8);
        }
#pragma unroll
        for (int q = 0; q < 4; ++q) {
            if (ee[q] < d) {
                a[0] += bf2f(v[q].x & 0xffffu);
                a[1] += bf2f(v[q].x >> 16);
                a[2] += bf2f(v[q].y & 0xffffu);
                a[3] += bf2f(v[q].y >> 16);
                a[4] += bf2f(v[q].z & 0xffffu);
                a[5] += bf2f(v[q].z >> 16);
                a[6] += bf2f(v[q].w & 0xffffu);
                a[7] += bf2f(v[q].w >> 16);
            }
        }
    }
    // reduce across the 4 edge-groups (lanes stride 16)
#pragma unroll
    for (int j = 0; j < 8; ++j) {
        a[j] += __shfl_xor(a[j], 16);
        a[j] += __shfl_xor(a[j], 32);
    }
    if (eg == 0) {
        float inv = 1.f / fmaxf((float)d, 1.f);
        uint4 o;
        o.x = pack2(a[0] * inv, a[1] * inv);
        o.y = pack2(a[2] * inv, a[3] * inv);
        o.z = pack2(a[4] * inv, a[5] * inv);
        o.w = pack2(a[6] * inv, a[7] * inv);
        *(uint4*)(mean_b + (size_t)wid * DH + cs * 8) = o;
    }
}

// ---------------- MFMA GEMM ----------------
template <bool LAST>
__global__ __launch_bounds__(256) void gemm_mfma(
    const ushort* __restrict__ tb,
    const ushort* __restrict__ mean_b,
    void* __restrict__ h_out,
    const ushort* __restrict__ Wp,
    const float* __restrict__ bsum,
    const ushort* __restrict__ lWp,
    const float* __restrict__ linb)
{
    __shared__ ushort As[64][136];

    const int t = threadIdx.x, lane = t & 63, w = t >> 6;
    const int l15 = lane & 15, l4 = lane >> 4;
    const int row0 = blockIdx.x * 64;

    f32x4 acc[4][2];
    {
        float4 b0 = *(const float4*)(bsum + (2 * w) * 16 + l4 * 4);
        float4 b1 = *(const float4*)(bsum + (2 * w + 1) * 16 + l4 * 4);
#pragma unroll
        for (int rt = 0; rt < 4; ++rt) {
            acc[rt][0] = f32x4{b0.x, b0.y, b0.z, b0.w};
            acc[rt][1] = f32x4{b1.x, b1.y, b1.z, b1.w};
        }
    }

    for (int seg = 0; seg < 4; ++seg) {
        __syncthreads();
        const ushort* srcbase = (seg < NR) ? (mean_b + (size_t)seg * NN * DH) : tb;
#pragma unroll
        for (int i = 0; i < 4; ++i) {
            int q = i * 256 + t;
            int r = q >> 4, c = q & 15;
            int node = row0 + r;
            uint4 v = make_uint4(0, 0, 0, 0);
            if (node < NN) v = *(const uint4*)(srcbase + (size_t)node * DH + c * 8);
            *(uint4*)(&As[r][c * 8]) = v;
        }
        __syncthreads();
        const ushort* wseg = Wp + (size_t)seg * 32768;
#pragma unroll
        for (int kc = 0; kc < 4; ++kc) {
            const ushort* wkc = wseg + kc * 8192;
            short8 bh0 = *(const short8*)(wkc + (2 * w) * 1024 + lane * 8);
            short8 bl0 = *(const short8*)(wkc + (2 * w) * 1024 + 512 + lane * 8);
            short8 bh1 = *(const short8*)(wkc + (2 * w + 1) * 1024 + lane * 8);
            short8 bl1 = *(const short8*)(wkc + (2 * w + 1) * 1024 + 512 + lane * 8);
#pragma unroll
            for (int rt = 0; rt < 4; ++rt) {
                short8 a = *(const short8*)(&As[rt * 16 + l15][kc * 32 + l4 * 8]);
                acc[rt][0] = __builtin_amdgcn_mfma_f32_16x16x32_bf16(bh0, a, acc[rt][0], 0, 0, 0);
                acc[rt][0] = __builtin_amdgcn_mfma_f32_16x16x32_bf16(bl0, a, acc[rt][0], 0, 0, 0);
                acc[rt][1] = __builtin_amdgcn_mfma_f32_16x16x32_bf16(bh1, a, acc[rt][1], 0, 0, 0);
                acc[rt][1] = __builtin_amdgcn_mfma_f32_16x16x32_bf16(bl1, a, acc[rt][1], 0, 0, 0);
            }
        }
    }

    if constexpr (!LAST) {
        ushort* hb = (ushort*)h_out;
#pragma unroll
        for (int rt = 0; rt < 4; ++rt) {
            int node = row0 + rt * 16 + l15;
            if (node < NN) {
#pragma unroll
                for (int j = 0; j < 2; ++j) {
                    int c0 = (2 * w + j) * 16 + l4 * 4;
                    uint2 o;
                    o.x = pack2(fmaxf(acc[rt][j][0], 0.f), fmaxf(acc[rt][j][1], 0.f));
                    o.y = pack2(fmaxf(acc[rt][j][2], 0.f), fmaxf(acc[rt][j][3], 0.f));
                    *(uint2*)(hb + (size_t)node * DH + c0) = o;
                }
            }
        }
    } else {
        __syncthreads();
#pragma unroll
        for (int rt = 0; rt < 4; ++rt) {
            int rl = rt * 16 + l15;
#pragma unroll
            for (int j = 0; j < 2; ++j) {
                int c0 = (2 * w + j) * 16 + l4 * 4;
                uint2 o;
                o.x = pack2(fmaxf(acc[rt][j][0], 0.f), fmaxf(acc[rt][j][1], 0.f));
                o.y = pack2(fmaxf(acc[rt][j][2], 0.f), fmaxf(acc[rt][j][3], 0.f));
                *(uint2*)(&As[rl][c0]) = o;
            }
        }
        __syncthreads();
        f32x4 acc2[2];
        {
            float4 c0 = *(const float4*)(linb + l4 * 4);
            float4 c1 = *(const float4*)(linb + 16 + l4 * 4);
            acc2[0] = f32x4{c0.x, c0.y, c0.z, c0.w};
            acc2[1] = f32x4{c1.x, c1.y, c1.z, c1.w};
        }
#pragma unroll
        for (int kc = 0; kc < 4; ++kc) {
            short8 a = *(const short8*)(&As[w * 16 + l15][kc * 32 + l4 * 8]);
#pragma unroll
            for (int j = 0; j < 2; ++j) {
                short8 bh = *(const short8*)(lWp + (kc * 2 + j) * 1024 + lane * 8);
                short8 bl = *(const short8*)(lWp + (kc * 2 + j) * 1024 + 512 + lane * 8);
                acc2[j] = __builtin_amdgcn_mfma_f32_16x16x32_bf16(bh, a, acc2[j], 0, 0, 0);
                acc2[j] = __builtin_amdgcn_mfma_f32_16x16x32_bf16(bl, a, acc2[j], 0, 0, 0);
            }
        }
        float* outp = (float*)h_out;
        int node = row0 + w * 16 + l15;
        if (node < NN) {
#pragma unroll
            for (int j = 0; j < 2; ++j) {
                *(f32x4*)(outp + (size_t)node * 32 + j * 16 + l4 * 4) = acc2[j];
            }
        }
    }
}

extern "C" void kernel_launch(void* const* d_in, const int* in_sizes, int n_in,
                              void* d_out, int out_size, void* d_ws, size_t ws_size,
                              hipStream_t stream) {
    const float* x = (const float*)d_in[0];
    const int* ei = (const int*)d_in[1];
    const float* Wn = (const float*)d_in[2];
    const float* Wr = (const float*)d_in[3];
    const float* bc = (const float*)d_in[4];
    const float* linW = (const float*)d_in[5];
    const float* linb = (const float*)d_in[6];
    float* out = (float*)d_out;

    char* p = (char*)d_ws;
    int* bcnt = (int*)p;     p += 4096;                       // 588 used
    int* bbase = (int*)p;    p += 4096;
    int* offs = (int*)p;     p += (size_t)NR * NN * 4;
    int* deg = (int*)p;      p += (size_t)NR * NN * 4;
    int* csr = (int*)p;      p += (size_t)NR * NE * 4;
    ushort* Wpack = (ushort*)p; p += (size_t)264 * 1024 * 2;  // 540 KB
    float* bsum = (float*)p; p += 4096;
    ushort* xb = (ushort*)p;  p += (size_t)NN * DH * 2;
    ushort* h1b = (ushort*)p; p += (size_t)NN * DH * 2;
    ushort* mean_b = (ushort*)p; p += (size_t)NR * NN * DH * 2;
    uint* pairs = (uint*)mean_b;  // alias: pairs consumed before mean_b written

    hipMemsetAsync(bcnt, 0, NBT * 4, stream);

    int eb = (NR * NE + 255) / 256;  // 7500
    bucket_kernel<<<eb, 256, 0, stream>>>(ei, bcnt, pairs);
    bscan_kernel<<<1, 1024, 0, stream>>>(bcnt, bbase);
    csr_kernel<<<NBT, 256, 0, stream>>>(pairs, bcnt, bbase, csr, offs, deg);
    prep_kernel<<<66, 256, 0, stream>>>(Wn, Wr, linW, Wpack);
    bias_kernel<<<1, 256, 0, stream>>>(bc, bsum);
    conv_kernel<<<(NN * DH / 4 + 255) / 256, 256, 0, stream>>>(x, xb);

    int lb = (NN + 63) / 64;  // 782
    int ab = (NR * NN * 64 + 255) / 256;  // 37500

    // layer 1
    aggr_kernel<<<ab, 256, 0, stream>>>(xb, mean_b, csr, offs, deg);
    gemm_mfma<false><<<lb, 256, 0, stream>>>(xb, mean_b, h1b, Wpack, bsum,
                                             nullptr, nullptr);
    // layer 2
    aggr_kernel<<<ab, 256, 0, stream>>>(h1b, mean_b, csr, offs, deg);
    gemm_mfma<true><<<lb, 256, 0, stream>>>(h1b, mean_b, out,
                                            Wpack + (size_t)128 * 1024, bsum + DH,
                                            Wpack + (size_t)256 * 1024, linb);
}

// Round 6
// 231.523 us; speedup vs baseline: 4.4164x; 4.4164x over previous
//
#include <hip/hip_runtime.h>

#define NN 50000
#define NE 640000
#define NR 3
#define DH 128
#define ET (NR * NE)           // 1,920,000 edges total

#define BK 256                 // nodes per bucket
#define NBK 196                // buckets per relation: ceil(50000/256)
#define NBT (NR * NBK)         // 588 total buckets
#define NCH 512                // edge chunks
#define CH (ET / NCH)          // 3750 edges per chunk (exact)

typedef __attribute__((ext_vector_type(8))) short short8;
typedef __attribute__((ext_vector_type(4))) float f32x4;

__device__ __forceinline__ float bf2f(uint u) { return __uint_as_float(u << 16); }
__device__ __forceinline__ uint f2bf(float f) {
    uint u = __float_as_uint(f);
    u += 0x7fff + ((u >> 16) & 1);  // round-to-nearest-even
    return u >> 16;
}
__device__ __forceinline__ uint pack2(float a, float b) { return f2bf(a) | (f2bf(b) << 16); }

// ---------------- pass 1: per-chunk LDS histogram of 588 buckets ----------------
__global__ __launch_bounds__(256) void hist_kernel(const int* __restrict__ ei,
                                                   int* __restrict__ gcnt) {
    __shared__ int hist[NBT];
    int g = blockIdx.x, t = threadIdx.x;
    for (int i = t; i < NBT; i += 256) hist[i] = 0;
    __syncthreads();
    int e0 = g * CH;
    for (int i = t; i < CH; i += 256) {
        int e = e0 + i;
        int r = (e >= 2 * NE) ? 2 : (e >= NE ? 1 : 0);
        int le = e - r * NE;
        int dst = ei[r * 2 * NE + NE + le];
        atomicAdd(&hist[r * NBK + (dst >> 8)], 1);
    }
    __syncthreads();
    for (int i = t; i < NBT; i += 256) gcnt[g * NBT + i] = hist[i];
}

// ---------------- pass 2a: per-bucket scan over chunk counts ----------------
__global__ __launch_bounds__(256) void cscan_kernel(const int* __restrict__ gcnt,
                                                    int* __restrict__ gbase,
                                                    int* __restrict__ btot) {
    int b = blockIdx.x, t = threadIdx.x;  // 512 values, 2 per thread
    int v0 = gcnt[(2 * t) * NBT + b];
    int v1 = gcnt[(2 * t + 1) * NBT + b];
    int s = v0 + v1;
    int lane = t & 63, w = t >> 6;
    int sc = s;
#pragma unroll
    for (int d = 1; d < 64; d <<= 1) {
        int u = __shfl_up(sc, d);
        if (lane >= d) sc += u;
    }
    __shared__ int ws[4];
    if (lane == 63) ws[w] = sc;
    __syncthreads();
    int add = 0;
#pragma unroll
    for (int q = 0; q < 3; ++q)
        if (q < w) add += ws[q];
    int incl = sc + add;
    int excl = incl - s;
    gbase[(2 * t) * NBT + b] = excl;
    gbase[(2 * t + 1) * NBT + b] = excl + v0;
    if (t == 255) btot[b] = incl;
}

// ---------------- pass 2b: bucket-base exclusive scan (588 values) ----------------
__global__ __launch_bounds__(1024) void bscan_kernel(const int* __restrict__ btot,
                                                     int* __restrict__ bbase) {
    int t = threadIdx.x;
    int v = (t < NBT) ? btot[t] : 0;
    int lane = t & 63, w = t >> 6;
    int s = v;
#pragma unroll
    for (int d = 1; d < 64; d <<= 1) {
        int u = __shfl_up(s, d);
        if (lane >= d) s += u;
    }
    __shared__ int ws[16];
    if (lane == 63) ws[w] = s;
    __syncthreads();
    if (t < 16) {
        int wv = ws[t];
#pragma unroll
        for (int d = 1; d < 16; d <<= 1) {
            int u = __shfl_up(wv, d);
            if (t >= d) wv += u;
        }
        ws[t] = wv;
    }
    __syncthreads();
    int incl = s + (w == 0 ? 0 : ws[w - 1]);
    if (t < NBT) bbase[t] = incl - v;  // exclusive
}

// ---------------- pass 3: scatter pairs via LDS cursors (no global atomics) ----------------
__global__ __launch_bounds__(256) void scatter_kernel(const int* __restrict__ ei,
                                                      const int* __restrict__ gbase,
                                                      const int* __restrict__ bbase,
                                                      uint* __restrict__ pairs) {
    __shared__ int cur[NBT];
    int g = blockIdx.x, t = threadIdx.x;
    for (int i = t; i < NBT; i += 256) cur[i] = bbase[i] + gbase[g * NBT + i];
    __syncthreads();
    int e0 = g * CH;
    for (int i = t; i < CH; i += 256) {
        int e = e0 + i;
        int r = (e >= 2 * NE) ? 2 : (e >= NE ? 1 : 0);
        int le = e - r * NE;
        int src = ei[r * 2 * NE + le];
        int dst = ei[r * 2 * NE + NE + le];
        int b = r * NBK + (dst >> 8);
        int pos = atomicAdd(&cur[b], 1);
        pairs[pos] = ((uint)src << 8) | (uint)(dst & 255);
    }
}

// ---------------- level 2: per-bucket LDS histogram + scan + scatter ----------------
__global__ __launch_bounds__(256) void csr_kernel(const uint* __restrict__ pairs,
                                                  const int* __restrict__ btot,
                                                  const int* __restrict__ bbase,
                                                  int* __restrict__ csr,
                                                  int* __restrict__ offs,
                                                  int* __restrict__ deg) {
    int b = blockIdx.x;            // 0..587
    int r = b / NBK;
    int n0 = (b - r * NBK) * BK;   // first node (within relation)
    int cnt = btot[b];
    int base = bbase[b];
    int t = threadIdx.x;

    __shared__ int hist[BK];
    __shared__ int cur[BK];
    __shared__ int ws[4];
    hist[t] = 0;
    __syncthreads();
    const uint* pp = pairs + base;
    for (int i = t; i < cnt; i += 256) atomicAdd(&hist[pp[i] & 255u], 1);
    __syncthreads();

    // exclusive scan of hist[256]
    int lane = t & 63, w = t >> 6;
    int v = hist[t], s = v;
#pragma unroll
    for (int d = 1; d < 64; d <<= 1) {
        int u = __shfl_up(s, d);
        if (lane >= d) s += u;
    }
    if (lane == 63) ws[w] = s;
    __syncthreads();
    int add = 0;
#pragma unroll
    for (int q = 0; q < 3; ++q)
        if (q < w) add += ws[q];
    int excl = s + add - v;

    int node = n0 + t;
    if (node < NN) {
        offs[r * NN + node] = base + excl;  // absolute into csr
        deg[r * NN + node] = v;
    }
    cur[t] = excl;
    __syncthreads();

    for (int i = t; i < cnt; i += 256) {
        uint pk = pp[i];
        int pos = atomicAdd(&cur[pk & 255u], 1);
        csr[base + pos] = (int)(pk >> 8);
    }
}

// ---------------- weight prep: pack W into MFMA B-fragment layout, hi/lo bf16 split
__global__ __launch_bounds__(256) void prep_kernel(const float* __restrict__ Wn,
                                                   const float* __restrict__ Wr,
                                                   const float* __restrict__ linW,
                                                   ushort* __restrict__ Wpack) {
    int tid = blockIdx.x * 256 + threadIdx.x;
    if (tid >= 264 * 64) return;
    int f = tid >> 6, lane = tid & 63;
    int l15 = lane & 15, l4 = lane >> 4;
    ushort hi8[8], lo8[8];
    if (f < 256) {
        int layer = f >> 7, seg = (f >> 5) & 3, kc = (f >> 3) & 3, nb = f & 7;
        int col = nb * 16 + l15;
        int kb = kc * 32 + l4 * 8;
#pragma unroll
        for (int e = 0; e < 8; ++e) {
            int k = kb + e;
            float v;
            if (seg < 3) {
                v = Wn[(((size_t)layer * 3 + seg) * 128 + k) * 128 + col];
            } else {
                const float* base = Wr + (size_t)layer * 3 * 16384;
                v = base[k * 128 + col] + base[16384 + k * 128 + col] +
                    base[32768 + k * 128 + col];
            }
            uint h = f2bf(v);
            float rem = v - bf2f(h);
            hi8[e] = (ushort)h;
            lo8[e] = (ushort)f2bf(rem);
        }
    } else {
        int g = f - 256;
        int kc = g >> 1, nb = g & 1;
        int col = nb * 16 + l15;
        int kb = kc * 32 + l4 * 8;
#pragma unroll
        for (int e = 0; e < 8; ++e) {
            float v = linW[(kb + e) * 32 + col];
            uint h = f2bf(v);
            float rem = v - bf2f(h);
            hi8[e] = (ushort)h;
            lo8[e] = (ushort)f2bf(rem);
        }
    }
    *(short8*)(Wpack + (size_t)f * 1024 + lane * 8) = *(short8*)hi8;
    *(short8*)(Wpack + (size_t)f * 1024 + 512 + lane * 8) = *(short8*)lo8;
}

__global__ __launch_bounds__(256) void bias_kernel(const float* __restrict__ bc,
                                                   float* __restrict__ bsum) {
    int tid = threadIdx.x;
    int l = tid >> 7, j = tid & 127;
    const float* bb = bc + l * 3 * DH;
    bsum[tid] = bb[j] + bb[DH + j] + bb[2 * DH + j];
}

__global__ __launch_bounds__(256) void conv_kernel(const float* __restrict__ x,
                                                   ushort* __restrict__ xb) {
    int gid = blockIdx.x * 256 + threadIdx.x;
    if (gid >= NN * DH / 4) return;
    float4 v = ((const float4*)x)[gid];
    uint2 o;
    o.x = pack2(v.x, v.y);
    o.y = pack2(v.z, v.w);
    ((uint2*)xb)[gid] = o;
}

// ---------------- aggregation: one wave per (rel,node); 4 edge-rows per vmem instr
__global__ __launch_bounds__(256) void aggr_kernel(const ushort* __restrict__ tb,
                                                   ushort* __restrict__ mean_b,
                                                   const int* __restrict__ csr,
                                                   const int* __restrict__ offs,
                                                   const int* __restrict__ deg) {
    int wid = (blockIdx.x * 256 + threadIdx.x) >> 6;
    wid = __builtin_amdgcn_readfirstlane(wid);
    if (wid >= NR * NN) return;
    int lane = threadIdx.x & 63;
    int eg = lane >> 4, cs = lane & 15;
    int base = offs[wid];
    int d = deg[wid];
    const int* lst = csr + base;

    float a[8] = {0.f, 0.f, 0.f, 0.f, 0.f, 0.f, 0.f, 0.f};
    for (int e = 0; e < d; e += 16) {  // 16 edges per iteration, 4 dwordx4 in flight
        uint4 v[4];
        int ee[4];
#pragma unroll
        for (int q = 0; q < 4; ++q) {
            ee[q] = e + q * 4 + eg;
            int idx = lst[min(ee[q], d - 1)];
            v[q] = *(const uint4*)(tb + (size_t)idx * DH + cs * 8);
        }
#pragma unroll
        for (int q = 0; q < 4; ++q) {
            if (ee[q] < d) {
                a[0] += bf2f(v[q].x & 0xffffu);
                a[1] += bf2f(v[q].x >> 16);
                a[2] += bf2f(v[q].y & 0xffffu);
                a[3] += bf2f(v[q].y >> 16);
                a[4] += bf2f(v[q].z & 0xffffu);
                a[5] += bf2f(v[q].z >> 16);
                a[6] += bf2f(v[q].w & 0xffffu);
                a[7] += bf2f(v[q].w >> 16);
            }
        }
    }
#pragma unroll
    for (int j = 0; j < 8; ++j) {
        a[j] += __shfl_xor(a[j], 16);
        a[j] += __shfl_xor(a[j], 32);
    }
    if (eg == 0) {
        float inv = 1.f / fmaxf((float)d, 1.f);
        uint4 o;
        o.x = pack2(a[0] * inv, a[1] * inv);
        o.y = pack2(a[2] * inv, a[3] * inv);
        o.z = pack2(a[4] * inv, a[5] * inv);
        o.w = pack2(a[6] * inv, a[7] * inv);
        *(uint4*)(mean_b + (size_t)wid * DH + cs * 8) = o;
    }
}

// ---------------- MFMA GEMM ----------------
template <bool LAST>
__global__ __launch_bounds__(256) void gemm_mfma(
    const ushort* __restrict__ tb,
    const ushort* __restrict__ mean_b,
    void* __restrict__ h_out,
    const ushort* __restrict__ Wp,
    const float* __restrict__ bsum,
    const ushort* __restrict__ lWp,
    const float* __restrict__ linb)
{
    __shared__ ushort As[64][136];

    const int t = threadIdx.x, lane = t & 63, w = t >> 6;
    const int l15 = lane & 15, l4 = lane >> 4;
    const int row0 = blockIdx.x * 64;

    f32x4 acc[4][2];
    {
        float4 b0 = *(const float4*)(bsum + (2 * w) * 16 + l4 * 4);
        float4 b1 = *(const float4*)(bsum + (2 * w + 1) * 16 + l4 * 4);
#pragma unroll
        for (int rt = 0; rt < 4; ++rt) {
            acc[rt][0] = f32x4{b0.x, b0.y, b0.z, b0.w};
            acc[rt][1] = f32x4{b1.x, b1.y, b1.z, b1.w};
        }
    }

    for (int seg = 0; seg < 4; ++seg) {
        __syncthreads();
        const ushort* srcbase = (seg < NR) ? (mean_b + (size_t)seg * NN * DH) : tb;
#pragma unroll
        for (int i = 0; i < 4; ++i) {
            int q = i * 256 + t;
            int r = q >> 4, c = q & 15;
            int node = row0 + r;
            uint4 v = make_uint4(0, 0, 0, 0);
            if (node < NN) v = *(const uint4*)(srcbase + (size_t)node * DH + c * 8);
            *(uint4*)(&As[r][c * 8]) = v;
        }
        __syncthreads();
        const ushort* wseg = Wp + (size_t)seg * 32768;
#pragma unroll
        for (int kc = 0; kc < 4; ++kc) {
            const ushort* wkc = wseg + kc * 8192;
            short8 bh0 = *(const short8*)(wkc + (2 * w) * 1024 + lane * 8);
            short8 bl0 = *(const short8*)(wkc + (2 * w) * 1024 + 512 + lane * 8);
            short8 bh1 = *(const short8*)(wkc + (2 * w + 1) * 1024 + lane * 8);
            short8 bl1 = *(const short8*)(wkc + (2 * w + 1) * 1024 + 512 + lane * 8);
#pragma unroll
            for (int rt = 0; rt < 4; ++rt) {
                short8 a = *(const short8*)(&As[rt * 16 + l15][kc * 32 + l4 * 8]);
                acc[rt][0] = __builtin_amdgcn_mfma_f32_16x16x32_bf16(bh0, a, acc[rt][0], 0, 0, 0);
                acc[rt][0] = __builtin_amdgcn_mfma_f32_16x16x32_bf16(bl0, a, acc[rt][0], 0, 0, 0);
                acc[rt][1] = __builtin_amdgcn_mfma_f32_16x16x32_bf16(bh1, a, acc[rt][1], 0, 0, 0);
                acc[rt][1] = __builtin_amdgcn_mfma_f32_16x16x32_bf16(bl1, a, acc[rt][1], 0, 0, 0);
            }
        }
    }

    if constexpr (!LAST) {
        ushort* hb = (ushort*)h_out;
#pragma unroll
        for (int rt = 0; rt < 4; ++rt) {
            int node = row0 + rt * 16 + l15;
            if (node < NN) {
#pragma unroll
                for (int j = 0; j < 2; ++j) {
                    int c0 = (2 * w + j) * 16 + l4 * 4;
                    uint2 o;
                    o.x = pack2(fmaxf(acc[rt][j][0], 0.f), fmaxf(acc[rt][j][1], 0.f));
                    o.y = pack2(fmaxf(acc[rt][j][2], 0.f), fmaxf(acc[rt][j][3], 0.f));
                    *(uint2*)(hb + (size_t)node * DH + c0) = o;
                }
            }
        }
    } else {
        __syncthreads();
#pragma unroll
        for (int rt = 0; rt < 4; ++rt) {
            int rl = rt * 16 + l15;
#pragma unroll
            for (int j = 0; j < 2; ++j) {
                int c0 = (2 * w + j) * 16 + l4 * 4;
                uint2 o;
                o.x = pack2(fmaxf(acc[rt][j][0], 0.f), fmaxf(acc[rt][j][1], 0.f));
                o.y = pack2(fmaxf(acc[rt][j][2], 0.f), fmaxf(acc[rt][j][3], 0.f));
                *(uint2*)(&As[rl][c0]) = o;
            }
        }
        __syncthreads();
        f32x4 acc2[2];
        {
            float4 c0 = *(const float4*)(linb + l4 * 4);
            float4 c1 = *(const float4*)(linb + 16 + l4 * 4);
            acc2[0] = f32x4{c0.x, c0.y, c0.z, c0.w};
            acc2[1] = f32x4{c1.x, c1.y, c1.z, c1.w};
        }
#pragma unroll
        for (int kc = 0; kc < 4; ++kc) {
            short8 a = *(const short8*)(&As[w * 16 + l15][kc * 32 + l4 * 8]);
#pragma unroll
            for (int j = 0; j < 2; ++j) {
                short8 bh = *(const short8*)(lWp + (kc * 2 + j) * 1024 + lane * 8);
                short8 bl = *(const short8*)(lWp + (kc * 2 + j) * 1024 + 512 + lane * 8);
                acc2[j] = __builtin_amdgcn_mfma_f32_16x16x32_bf16(bh, a, acc2[j], 0, 0, 0);
                acc2[j] = __builtin_amdgcn_mfma_f32_16x16x32_bf16(bl, a, acc2[j], 0, 0, 0);
            }
        }
        float* outp = (float*)h_out;
        int node = row0 + w * 16 + l15;
        if (node < NN) {
#pragma unroll
            for (int j = 0; j < 2; ++j) {
                *(f32x4*)(outp + (size_t)node * 32 + j * 16 + l4 * 4) = acc2[j];
            }
        }
    }
}

extern "C" void kernel_launch(void* const* d_in, const int* in_sizes, int n_in,
                              void* d_out, int out_size, void* d_ws, size_t ws_size,
                              hipStream_t stream) {
    const float* x = (const float*)d_in[0];
    const int* ei = (const int*)d_in[1];
    const float* Wn = (const float*)d_in[2];
    const float* Wr = (const float*)d_in[3];
    const float* bc = (const float*)d_in[4];
    const float* linW = (const float*)d_in[5];
    const float* linb = (const float*)d_in[6];
    float* out = (float*)d_out;

    char* p = (char*)d_ws;
    int* gcnt = (int*)p;     p += (size_t)NCH * NBT * 4;      // 1.2 MB
    int* gbase = (int*)p;    p += (size_t)NCH * NBT * 4;      // 1.2 MB
    int* btot = (int*)p;     p += 4096;
    int* bbase = (int*)p;    p += 4096;
    int* offs = (int*)p;     p += (size_t)NR * NN * 4;
    int* deg = (int*)p;      p += (size_t)NR * NN * 4;
    int* csr = (int*)p;      p += (size_t)ET * 4;
    ushort* Wpack = (ushort*)p; p += (size_t)264 * 1024 * 2;  // 540 KB
    float* bsum = (float*)p; p += 4096;
    ushort* xb = (ushort*)p;  p += (size_t)NN * DH * 2;
    ushort* h1b = (ushort*)p; p += (size_t)NN * DH * 2;
    ushort* mean_b = (ushort*)p; p += (size_t)NR * NN * DH * 2;
    uint* pairs = (uint*)mean_b;  // alias: pairs consumed before mean_b written

    hist_kernel<<<NCH, 256, 0, stream>>>(ei, gcnt);
    cscan_kernel<<<NBT, 256, 0, stream>>>(gcnt, gbase, btot);
    bscan_kernel<<<1, 1024, 0, stream>>>(btot, bbase);
    scatter_kernel<<<NCH, 256, 0, stream>>>(ei, gbase, bbase, pairs);
    csr_kernel<<<NBT, 256, 0, stream>>>(pairs, btot, bbase, csr, offs, deg);
    prep_kernel<<<66, 256, 0, stream>>>(Wn, Wr, linW, Wpack);
    bias_kernel<<<1, 256, 0, stream>>>(bc, bsum);
    conv_kernel<<<(NN * DH / 4 + 255) / 256, 256, 0, stream>>>(x, xb);

    int lb = (NN + 63) / 64;  // 782
    int ab = (NR * NN * 64 + 255) / 256;  // 37500

    // layer 1
    aggr_kernel<<<ab, 256, 0, stream>>>(xb, mean_b, csr, offs, deg);
    gemm_mfma<false><<<lb, 256, 0, stream>>>(xb, mean_b, h1b, Wpack, bsum,
                                             nullptr, nullptr);
    // layer 2
    aggr_kernel<<<ab, 256, 0, stream>>>(h1b, mean_b, csr, offs, deg);
    gemm_mfma<true><<<lb, 256, 0, stream>>>(h1b, mean_b, out,
                                            Wpack + (size_t)128 * 1024, bsum + DH,
                                            Wpack + (size_t)256 * 1024, linb);
}